// Round 5
// baseline (264.787 us; speedup 1.0000x reference)
//
#include <hip/hip_runtime.h>

#define NN 50000
#define NE 100000
#define NREL 64
#define D 64
#define BPR 8          // chunks (blocks) per relation
#define RCAP 1280      // per-relation bucket capacity (expected ~676)
#define SCAP 8192      // self-only bucket capacity (expected ~6766)

typedef unsigned long long u64;

// ws layout (bytes): packed [0, 400000) | cursor @512K (65 ints) |
// rbucket @516K (64*RCAP uints) | sbucket @1M (SCAP uints)
#define WS_CURSOR  (512 * 1024)
#define WS_RBUCKET (516 * 1024)
#define WS_SBUCKET (1024 * 1024)

__global__ void k_init(u64* __restrict__ packed, int* __restrict__ cursor) {
    int t = blockIdx.x * blockDim.x + threadIdx.x;
    for (int i = t; i < NN; i += gridDim.x * blockDim.x) packed[i] = 0ull;
    if (t < 65) cursor[t] = 0;
}

// one 64-bit atomicMax per edge: key = (e+1)<<22 | rel<<16 | src
__global__ void k_scatter(const int* __restrict__ edges, u64* __restrict__ packed) {
    int e = blockIdx.x * blockDim.x + threadIdx.x;
    if (e < NE) {
        int s = edges[e * 3 + 0];
        int r = edges[e * 3 + 1];
        int d = edges[e * 3 + 2];
        u64 key = ((u64)(e + 1) << 22) | ((u64)r << 16) | (u64)s;
        atomicMax(&packed[d], key);
    }
}

__global__ void k_fill(const u64* __restrict__ packed, int* __restrict__ cursor,
                       unsigned* __restrict__ rbucket, unsigned* __restrict__ sbucket) {
    int v = blockIdx.x * blockDim.x + threadIdx.x;
    if (v < NN) {
        u64 key = packed[v];
        if (key) {
            int r = (int)((key >> 16) & 63);
            int p = atomicAdd(&cursor[r], 1);
            if (p < RCAP) rbucket[r * RCAP + p] = ((unsigned)v << 16) | (unsigned)(key & 0xFFFF);
        } else {
            int p = atomicAdd(&cursor[64], 1);
            if (p < SCAP) sbucket[p] = (unsigned)v;
        }
    }
}

__device__ __forceinline__ float bcast(float x, int i) {
    return __int_as_float(__builtin_amdgcn_readlane(__float_as_int(x), i));
}

// nodes with in-edges: out[v] = h[src]@W[r] + h[v]@Wself   (single store, no RMW)
__global__ __launch_bounds__(512, 4) void k_rel(
    const float* __restrict__ h, const float* __restrict__ weight,
    const float* __restrict__ wself, const unsigned* __restrict__ rbucket,
    const int* __restrict__ cursor, float* __restrict__ out)
{
    __shared__ float lds_w[D * D];   // W[r]    16 KiB
    __shared__ float lds_ws[D * D];  // W_self  16 KiB

    const int lane = threadIdx.x & 63;
    const int wave = threadIdx.x >> 6;          // 8 waves
    const int r = blockIdx.x / BPR;
    const int chunk = blockIdx.x % BPR;
    const int cnt = min(cursor[r], RCAP);

    const int per = (cnt + BPR - 1) / BPR;
    const int begin = chunk * per;
    const int end = min(begin + per, cnt);
    if (begin >= end) return;                    // nothing for this chunk

    const float4* wsrc = reinterpret_cast<const float4*>(weight + (size_t)r * D * D);
    for (int t = threadIdx.x; t < D * D / 4; t += 512) {
        reinterpret_cast<float4*>(lds_w)[t] = wsrc[t];
        reinterpret_cast<float4*>(lds_ws)[t] = reinterpret_cast<const float4*>(wself)[t];
    }
    __syncthreads();

    const unsigned* seg = rbucket + r * RCAP;

    for (int g = begin + wave * 4; g < end; g += 8 * 4) {
        const int nact = min(4, end - g);

        int v[4], s[4];
        #pragma unroll
        for (int j = 0; j < 4; ++j) {
            unsigned ent = seg[(j < nact) ? (g + j) : g];   // broadcast load
            v[j] = (int)(ent >> 16);
            s[j] = (int)(ent & 0xFFFF);
        }

        float hs[4], hv[4];
        #pragma unroll
        for (int j = 0; j < 4; ++j) {
            hs[j] = h[(size_t)s[j] * D + lane];
            hv[j] = h[(size_t)v[j] * D + lane];
        }

        float acc[4]  = {0.f, 0.f, 0.f, 0.f};
        float accS[4] = {0.f, 0.f, 0.f, 0.f};
        #pragma unroll
        for (int i = 0; i < D; ++i) {
            const float w  = lds_w[i * D + lane];
            const float ws = lds_ws[i * D + lane];
            #pragma unroll
            for (int j = 0; j < 4; ++j) {
                acc[j]  = fmaf(bcast(hs[j], i), w,  acc[j]);
                accS[j] = fmaf(bcast(hv[j], i), ws, accS[j]);
            }
        }

        #pragma unroll
        for (int j = 0; j < 4; ++j)
            if (j < nact) out[(size_t)v[j] * D + lane] = acc[j] + accS[j];
    }
}

// nodes with NO in-edges: out[v] = h[v]@Wself
__global__ __launch_bounds__(256, 8) void k_self(
    const float* __restrict__ h, const float* __restrict__ wself,
    const unsigned* __restrict__ sbucket, const int* __restrict__ cursor,
    float* __restrict__ out)
{
    __shared__ float lds_ws[D * D];
    for (int t = threadIdx.x; t < D * D / 4; t += 256)
        reinterpret_cast<float4*>(lds_ws)[t] = reinterpret_cast<const float4*>(wself)[t];
    __syncthreads();

    const int lane = threadIdx.x & 63;
    const int wave = threadIdx.x >> 6;          // 4 waves
    const int cnt = min(cursor[64], SCAP);
    const int stride = gridDim.x * 4 * 4;

    for (int g = (blockIdx.x * 4 + wave) * 4; g < cnt; g += stride) {
        const int nact = min(4, cnt - g);

        int v[4];
        #pragma unroll
        for (int j = 0; j < 4; ++j)
            v[j] = (int)sbucket[(j < nact) ? (g + j) : g];

        float hv[4];
        #pragma unroll
        for (int j = 0; j < 4; ++j) hv[j] = h[(size_t)v[j] * D + lane];

        float acc[4] = {0.f, 0.f, 0.f, 0.f};
        #pragma unroll
        for (int i = 0; i < D; ++i) {
            const float ws = lds_ws[i * D + lane];
            #pragma unroll
            for (int j = 0; j < 4; ++j)
                acc[j] = fmaf(bcast(hv[j], i), ws, acc[j]);
        }

        #pragma unroll
        for (int j = 0; j < 4; ++j)
            if (j < nact) out[(size_t)v[j] * D + lane] = acc[j];
    }
}

extern "C" void kernel_launch(void* const* d_in, const int* in_sizes, int n_in,
                              void* d_out, int out_size, void* d_ws, size_t ws_size,
                              hipStream_t stream) {
    const float* h      = (const float*)d_in[0];
    const int*   edges  = (const int*)d_in[1];
    const float* weight = (const float*)d_in[2];
    const float* wself  = (const float*)d_in[3];
    float* out = (float*)d_out;

    char* ws = (char*)d_ws;
    u64*      packed  = (u64*)ws;
    int*      cursor  = (int*)(ws + WS_CURSOR);
    unsigned* rbucket = (unsigned*)(ws + WS_RBUCKET);
    unsigned* sbucket = (unsigned*)(ws + WS_SBUCKET);

    k_init<<<128, 256, 0, stream>>>(packed, cursor);
    k_scatter<<<(NE + 255) / 256, 256, 0, stream>>>(edges, packed);
    k_fill<<<(NN + 255) / 256, 256, 0, stream>>>(packed, cursor, rbucket, sbucket);
    k_rel<<<NREL * BPR, 512, 0, stream>>>(h, weight, wself, rbucket, cursor, out);
    k_self<<<64, 256, 0, stream>>>(h, wself, sbucket, cursor, out);
}

// Round 6
// 138.361 us; speedup vs baseline: 1.9137x; 1.9137x over previous
//
#include <hip/hip_runtime.h>

#define NN 50000
#define NE 100000
#define NREL 64
#define D 64
#define CPR 16         // chunk-blocks per relation
#define RCAP 1280      // per-relation bucket capacity (expected ~676)
#define SCAP 8192      // self-only bucket capacity (expected ~6766)

typedef unsigned long long u64;

// ws layout (bytes): packed [0,400000) | cursor @512K (65 ints) |
// rbucket @516K (64*RCAP uints = 327KB) | sbucket @1M (SCAP uints = 32KB)
#define WS_CURSOR  (512 * 1024)
#define WS_RBUCKET (516 * 1024)
#define WS_SBUCKET (1024 * 1024)

__global__ void k_init(u64* __restrict__ packed, int* __restrict__ cursor) {
    int t = blockIdx.x * blockDim.x + threadIdx.x;
    for (int i = t; i < NN; i += gridDim.x * blockDim.x) packed[i] = 0ull;
    if (t < 65) cursor[t] = 0;
}

// one 64-bit atomicMax per edge: key = (e+1)<<22 | rel<<16 | src
__global__ void k_scatter(const int* __restrict__ edges, u64* __restrict__ packed) {
    int e = blockIdx.x * blockDim.x + threadIdx.x;
    if (e < NE) {
        int s = edges[e * 3 + 0];
        int r = edges[e * 3 + 1];
        int d = edges[e * 3 + 2];
        u64 key = ((u64)(e + 1) << 22) | ((u64)r << 16) | (u64)s;
        atomicMax(&packed[d], key);
    }
}

__global__ void k_fill(const u64* __restrict__ packed, int* __restrict__ cursor,
                       unsigned* __restrict__ rbucket, unsigned* __restrict__ sbucket) {
    int v = blockIdx.x * blockDim.x + threadIdx.x;
    if (v < NN) {
        u64 key = packed[v];
        if (key) {
            int r = (int)((key >> 16) & 63);
            int p = atomicAdd(&cursor[r], 1);
            if (p < RCAP) rbucket[r * RCAP + p] = ((unsigned)v << 16) | (unsigned)(key & 0xFFFF);
        } else {
            int p = atomicAdd(&cursor[64], 1);
            if (p < SCAP) sbucket[p] = (unsigned)v;
        }
    }
}

__device__ __forceinline__ float bcast(float x, int i) {
    return __int_as_float(__builtin_amdgcn_readlane(__float_as_int(x), i));
}

// nodes with in-edges: out[v] = h[src]@W[r] + h[v]@Wself  (1 node/wave, no reg caps)
__global__ void k_rel(
    const float* __restrict__ h, const float* __restrict__ weight,
    const float* __restrict__ wself, const unsigned* __restrict__ rbucket,
    const int* __restrict__ cursor, float* __restrict__ out)
{
    __shared__ float lds_w[D * D];   // W[r]    16 KiB
    __shared__ float lds_ws[D * D];  // W_self  16 KiB

    const int lane = threadIdx.x & 63;
    const int wave = threadIdx.x >> 6;          // 4 waves / block
    const int r = blockIdx.x / CPR;
    const int chunk = blockIdx.x % CPR;
    const int cnt = min(cursor[r], RCAP);

    const int per = (cnt + CPR - 1) / CPR;
    const int begin = chunk * per;
    const int end = min(begin + per, cnt);
    if (begin >= end) return;                    // block-uniform, before any sync

    const float4* wsrc = reinterpret_cast<const float4*>(weight + (size_t)r * D * D);
    for (int t = threadIdx.x; t < D * D / 4; t += 256) {
        reinterpret_cast<float4*>(lds_w)[t] = wsrc[t];
        reinterpret_cast<float4*>(lds_ws)[t] = reinterpret_cast<const float4*>(wself)[t];
    }
    __syncthreads();

    const unsigned* __restrict__ seg = rbucket + r * RCAP;

    for (int g = begin + wave; g < end; g += 4) {
        const unsigned ent = seg[g];
        const int v = (int)(ent >> 16);
        const int s = (int)(ent & 0xFFFF);

        const float hs = h[(size_t)s * D + lane];
        const float hv = h[(size_t)v * D + lane];

        float acc = 0.f, accS = 0.f;
        #pragma unroll
        for (int i = 0; i < D; ++i) {
            acc  = fmaf(bcast(hs, i), lds_w[i * D + lane],  acc);
            accS = fmaf(bcast(hv, i), lds_ws[i * D + lane], accS);
        }
        out[(size_t)v * D + lane] = acc + accS;
    }
}

// nodes with NO in-edges: out[v] = h[v]@Wself  (1 node/wave, grid-stride)
__global__ void k_self(
    const float* __restrict__ h, const float* __restrict__ wself,
    const unsigned* __restrict__ sbucket, const int* __restrict__ cursor,
    float* __restrict__ out)
{
    __shared__ float lds_ws[D * D];
    for (int t = threadIdx.x; t < D * D / 4; t += 256)
        reinterpret_cast<float4*>(lds_ws)[t] = reinterpret_cast<const float4*>(wself)[t];
    __syncthreads();

    const int lane = threadIdx.x & 63;
    const int wave = threadIdx.x >> 6;          // 4 waves / block
    const int cnt = min(cursor[64], SCAP);
    const int nwaves = gridDim.x * 4;

    for (int g = blockIdx.x * 4 + wave; g < cnt; g += nwaves) {
        const int v = (int)sbucket[g];
        const float hv = h[(size_t)v * D + lane];

        float acc = 0.f;
        #pragma unroll
        for (int i = 0; i < D; ++i)
            acc = fmaf(bcast(hv, i), lds_ws[i * D + lane], acc);

        out[(size_t)v * D + lane] = acc;
    }
}

extern "C" void kernel_launch(void* const* d_in, const int* in_sizes, int n_in,
                              void* d_out, int out_size, void* d_ws, size_t ws_size,
                              hipStream_t stream) {
    const float* h      = (const float*)d_in[0];
    const int*   edges  = (const int*)d_in[1];
    const float* weight = (const float*)d_in[2];
    const float* wself  = (const float*)d_in[3];
    float* out = (float*)d_out;

    char* ws = (char*)d_ws;
    u64*      packed  = (u64*)ws;
    int*      cursor  = (int*)(ws + WS_CURSOR);
    unsigned* rbucket = (unsigned*)(ws + WS_RBUCKET);
    unsigned* sbucket = (unsigned*)(ws + WS_SBUCKET);

    k_init<<<128, 256, 0, stream>>>(packed, cursor);
    k_scatter<<<(NE + 255) / 256, 256, 0, stream>>>(edges, packed);
    k_fill<<<(NN + 255) / 256, 256, 0, stream>>>(packed, cursor, rbucket, sbucket);
    k_rel<<<NREL * CPR, 256, 0, stream>>>(h, weight, wself, rbucket, cursor, out);
    k_self<<<128, 256, 0, stream>>>(h, wself, sbucket, cursor, out);
}

// Round 7
// 75.419 us; speedup vs baseline: 3.5109x; 1.8346x over previous
//
#include <hip/hip_runtime.h>

#define NN 50000
#define NE 100000
#define NREL 64
#define D 64
#define CPR 16         // chunk-blocks per relation
#define RCAP 1280      // per-relation bucket capacity (expected ~676)
#define SCAP 8192      // self-only bucket capacity (expected ~6766)
#define CSTR 16        // cursor stride in ints (64 B per counter)

#define FILL_BLOCKS 64
#define FILL_ITERS  4  // 64 blocks * 256 thr * 4 = 65536 >= NN

typedef unsigned long long u64;

// ws layout (bytes): packed [0,400000) | cursor @512K (65*CSTR ints = 4160B) |
// rbucket @520K (64*RCAP uints = 327KB) | sbucket @1M (SCAP uints = 32KB)
#define WS_CURSOR  (512 * 1024)
#define WS_RBUCKET (520 * 1024)
#define WS_SBUCKET (1024 * 1024)

__global__ void k_init(u64* __restrict__ packed, int* __restrict__ cursor) {
    int t = blockIdx.x * blockDim.x + threadIdx.x;
    for (int i = t; i < NN; i += gridDim.x * blockDim.x) packed[i] = 0ull;
    if (t < 65) cursor[t * CSTR] = 0;
}

// one 64-bit atomicMax per edge: key = (e+1)<<22 | rel<<16 | src
__global__ void k_scatter(const int* __restrict__ edges, u64* __restrict__ packed) {
    int e = blockIdx.x * blockDim.x + threadIdx.x;
    if (e < NE) {
        int s = edges[e * 3 + 0];
        int r = edges[e * 3 + 1];
        int d = edges[e * 3 + 2];
        u64 key = ((u64)(e + 1) << 22) | ((u64)r << 16) | (u64)s;
        atomicMax(&packed[d], key);
    }
}

// block-aggregated bucket fill: LDS histogram -> 1 global atomic per (block, rel)
__global__ __launch_bounds__(256) void k_fill(
    const u64* __restrict__ packed, int* __restrict__ cursor,
    unsigned* __restrict__ rbucket, unsigned* __restrict__ sbucket)
{
    __shared__ int hcnt[65];
    __shared__ int hbase[65];
    const int t = threadIdx.x;
    if (t < 65) hcnt[t] = 0;
    __syncthreads();

    int      myr[FILL_ITERS];
    int      myslot[FILL_ITERS];
    unsigned myent[FILL_ITERS];

    #pragma unroll
    for (int it = 0; it < FILL_ITERS; ++it) {
        const int v = (blockIdx.x * FILL_ITERS + it) * 256 + t;
        myr[it] = -1;
        if (v < NN) {
            u64 key = packed[v];
            if (key) {
                myr[it]   = (int)((key >> 16) & 63);
                myent[it] = ((unsigned)v << 16) | (unsigned)(key & 0xFFFF);
            } else {
                myr[it]   = 64;
                myent[it] = (unsigned)v;
            }
            myslot[it] = atomicAdd(&hcnt[myr[it]], 1);
        }
    }
    __syncthreads();
    if (t < 65 && hcnt[t] > 0)
        hbase[t] = atomicAdd(&cursor[t * CSTR], hcnt[t]);
    __syncthreads();

    #pragma unroll
    for (int it = 0; it < FILL_ITERS; ++it) {
        const int r = myr[it];
        if (r >= 0) {
            const int p = hbase[r] + myslot[it];
            if (r < 64) { if (p < RCAP) rbucket[r * RCAP + p] = myent[it]; }
            else        { if (p < SCAP) sbucket[p] = myent[it]; }
        }
    }
}

__device__ __forceinline__ float bcast(float x, int i) {
    return __int_as_float(__builtin_amdgcn_readlane(__float_as_int(x), i));
}

// nodes with in-edges: out[v] = h[src]@W[r] + h[v]@Wself  (1 node/wave, no reg caps)
__global__ void k_rel(
    const float* __restrict__ h, const float* __restrict__ weight,
    const float* __restrict__ wself, const unsigned* __restrict__ rbucket,
    const int* __restrict__ cursor, float* __restrict__ out)
{
    __shared__ float lds_w[D * D];   // W[r]    16 KiB
    __shared__ float lds_ws[D * D];  // W_self  16 KiB

    const int lane = threadIdx.x & 63;
    const int wave = threadIdx.x >> 6;          // 4 waves / block
    const int r = blockIdx.x / CPR;
    const int chunk = blockIdx.x % CPR;
    const int cnt = min(cursor[r * CSTR], RCAP);

    const int per = (cnt + CPR - 1) / CPR;
    const int begin = chunk * per;
    const int end = min(begin + per, cnt);
    if (begin >= end) return;                    // block-uniform, before any sync

    const float4* wsrc = reinterpret_cast<const float4*>(weight + (size_t)r * D * D);
    for (int t = threadIdx.x; t < D * D / 4; t += 256) {
        reinterpret_cast<float4*>(lds_w)[t] = wsrc[t];
        reinterpret_cast<float4*>(lds_ws)[t] = reinterpret_cast<const float4*>(wself)[t];
    }
    __syncthreads();

    const unsigned* __restrict__ seg = rbucket + r * RCAP;

    for (int g = begin + wave; g < end; g += 4) {
        const unsigned ent = seg[g];
        const int v = (int)(ent >> 16);
        const int s = (int)(ent & 0xFFFF);

        const float hs = h[(size_t)s * D + lane];
        const float hv = h[(size_t)v * D + lane];

        float acc = 0.f, accS = 0.f;
        #pragma unroll
        for (int i = 0; i < D; ++i) {
            acc  = fmaf(bcast(hs, i), lds_w[i * D + lane],  acc);
            accS = fmaf(bcast(hv, i), lds_ws[i * D + lane], accS);
        }
        out[(size_t)v * D + lane] = acc + accS;
    }
}

// nodes with NO in-edges: out[v] = h[v]@Wself  (1 node/wave, grid-stride)
__global__ void k_self(
    const float* __restrict__ h, const float* __restrict__ wself,
    const unsigned* __restrict__ sbucket, const int* __restrict__ cursor,
    float* __restrict__ out)
{
    __shared__ float lds_ws[D * D];
    for (int t = threadIdx.x; t < D * D / 4; t += 256)
        reinterpret_cast<float4*>(lds_ws)[t] = reinterpret_cast<const float4*>(wself)[t];
    __syncthreads();

    const int lane = threadIdx.x & 63;
    const int wave = threadIdx.x >> 6;          // 4 waves / block
    const int cnt = min(cursor[64 * CSTR], SCAP);
    const int nwaves = gridDim.x * 4;

    for (int g = blockIdx.x * 4 + wave; g < cnt; g += nwaves) {
        const int v = (int)sbucket[g];
        const float hv = h[(size_t)v * D + lane];

        float acc = 0.f;
        #pragma unroll
        for (int i = 0; i < D; ++i)
            acc = fmaf(bcast(hv, i), lds_ws[i * D + lane], acc);

        out[(size_t)v * D + lane] = acc;
    }
}

extern "C" void kernel_launch(void* const* d_in, const int* in_sizes, int n_in,
                              void* d_out, int out_size, void* d_ws, size_t ws_size,
                              hipStream_t stream) {
    const float* h      = (const float*)d_in[0];
    const int*   edges  = (const int*)d_in[1];
    const float* weight = (const float*)d_in[2];
    const float* wself  = (const float*)d_in[3];
    float* out = (float*)d_out;

    char* ws = (char*)d_ws;
    u64*      packed  = (u64*)ws;
    int*      cursor  = (int*)(ws + WS_CURSOR);
    unsigned* rbucket = (unsigned*)(ws + WS_RBUCKET);
    unsigned* sbucket = (unsigned*)(ws + WS_SBUCKET);

    k_init<<<128, 256, 0, stream>>>(packed, cursor);
    k_scatter<<<(NE + 255) / 256, 256, 0, stream>>>(edges, packed);
    k_fill<<<FILL_BLOCKS, 256, 0, stream>>>(packed, cursor, rbucket, sbucket);
    k_rel<<<NREL * CPR, 256, 0, stream>>>(h, weight, wself, rbucket, cursor, out);
    k_self<<<128, 256, 0, stream>>>(h, wself, sbucket, cursor, out);
}

// Round 8
// 46.809 us; speedup vs baseline: 5.6568x; 1.6112x over previous
//
#include <hip/hip_runtime.h>

#define NN 50000
#define NE 100000
#define NREL 64
#define D 64
#define RCAP 1280      // per-relation bucket capacity (expected ~676, +23 sigma)
#define SCAP 8192      // self-only bucket capacity (expected ~6766)
#define CSTR 16        // cursor stride in ints (64 B per counter)
#define NGR  (RCAP / 64)   // 20 node-groups per relation
#define WPR  (NGR * 2)     // 40 waves per relation (x2 output halves)
#define WPS  ((SCAP / 64) * 2)  // 256 self waves
#define FILL_BLOCKS 64
#define FILL_ITERS  4
#define LDH_PAD 68     // floats per lane-row in LDS (272 B, 16B-aligned, breaks bank alias)

typedef unsigned long long u64;

// ws layout (bytes): packed [0,400000) | cursor @512K | rbucket @520K | sbucket @1M
#define WS_CURSOR  (512 * 1024)
#define WS_RBUCKET (520 * 1024)
#define WS_SBUCKET (1024 * 1024)

__global__ void k_init(u64* __restrict__ packed, int* __restrict__ cursor) {
    int t = blockIdx.x * blockDim.x + threadIdx.x;
    for (int i = t; i < NN; i += gridDim.x * blockDim.x) packed[i] = 0ull;
    if (t < 65) cursor[t * CSTR] = 0;
}

__global__ void k_scatter(const int* __restrict__ edges, u64* __restrict__ packed) {
    int e = blockIdx.x * blockDim.x + threadIdx.x;
    if (e < NE) {
        int s = edges[e * 3 + 0];
        int r = edges[e * 3 + 1];
        int d = edges[e * 3 + 2];
        u64 key = ((u64)(e + 1) << 22) | ((u64)r << 16) | (u64)s;
        atomicMax(&packed[d], key);
    }
}

// block-aggregated bucket fill: LDS histogram -> 1 global atomic per (block, rel)
__global__ __launch_bounds__(256) void k_fill(
    const u64* __restrict__ packed, int* __restrict__ cursor,
    unsigned* __restrict__ rbucket, unsigned* __restrict__ sbucket)
{
    __shared__ int hcnt[65];
    __shared__ int hbase[65];
    const int t = threadIdx.x;
    if (t < 65) hcnt[t] = 0;
    __syncthreads();

    int      myr[FILL_ITERS];
    int      myslot[FILL_ITERS];
    unsigned myent[FILL_ITERS];

    #pragma unroll
    for (int it = 0; it < FILL_ITERS; ++it) {
        const int v = (blockIdx.x * FILL_ITERS + it) * 256 + t;
        myr[it] = -1;
        if (v < NN) {
            u64 key = packed[v];
            if (key) {
                myr[it]   = (int)((key >> 16) & 63);
                myent[it] = ((unsigned)v << 16) | (unsigned)(key & 0xFFFF);
            } else {
                myr[it]   = 64;
                myent[it] = (unsigned)v;
            }
            myslot[it] = atomicAdd(&hcnt[myr[it]], 1);
        }
    }
    __syncthreads();
    if (t < 65 && hcnt[t] > 0)
        hbase[t] = atomicAdd(&cursor[t * CSTR], hcnt[t]);
    __syncthreads();

    #pragma unroll
    for (int it = 0; it < FILL_ITERS; ++it) {
        const int r = myr[it];
        if (r >= 0) {
            const int p = hbase[r] + myslot[it];
            if (r < 64) { if (p < RCAP) rbucket[r * RCAP + p] = myent[it]; }
            else        { if (p < SCAP) sbucket[p] = myent[it]; }
        }
    }
}

// lane = node. One wave (64-thread block) handles 64 bucket entries x 32 output
// columns. W rows are wave-uniform -> scalar loads; h row per-lane via LDS.
__global__ __launch_bounds__(64) void k_compute(
    const float* __restrict__ h, const float* __restrict__ weight,
    const float* __restrict__ wself, const unsigned* __restrict__ rbucket,
    const unsigned* __restrict__ sbucket, const int* __restrict__ cursor,
    float* __restrict__ out)
{
    __shared__ float lds_h[64 * LDH_PAD];
    const int lane = threadIdx.x;

    int r, ngroup, ohalf;
    const unsigned* __restrict__ seg;
    bool isRel;
    if (blockIdx.x < NREL * WPR) {
        r = blockIdx.x / WPR;
        const int w = blockIdx.x % WPR;
        ngroup = w >> 1; ohalf = w & 1;
        seg = rbucket + r * RCAP;
        isRel = true;
    } else {
        const int w = blockIdx.x - NREL * WPR;
        ngroup = w >> 1; ohalf = w & 1;
        seg = sbucket;
        r = 64;
        isRel = false;
    }

    const int cnt = min(cursor[r * CSTR], isRel ? RCAP : SCAP);
    const int g0 = ngroup * 64;
    if (g0 >= cnt) return;                       // whole-wave exit, no barriers used

    const unsigned ent = seg[min(g0 + lane, cnt - 1)];
    const int v = isRel ? (int)(ent >> 16) : (int)ent;
    const int s = (int)(ent & 0xFFFF);           // src, valid only when isRel

    const int obase = ohalf * 32;
    float* __restrict__ myrow = lds_h + lane * LDH_PAD;
    float4* __restrict__ myrow4 = reinterpret_cast<float4*>(myrow);

    float acc[32];
    #pragma unroll
    for (int oo = 0; oo < 32; ++oo) acc[oo] = 0.f;

    // ---- pass 1: agg = h[s] @ W[r]  (relation buckets only) ----
    if (isRel) {
        const float4* __restrict__ hsrc = reinterpret_cast<const float4*>(h + (size_t)s * D);
        #pragma unroll
        for (int k = 0; k < 16; ++k) myrow4[k] = hsrc[k];

        const float* __restrict__ wbase = weight + (size_t)r * D * D + obase;
        #pragma unroll 4
        for (int i4 = 0; i4 < 16; ++i4) {
            const float4 hi = myrow4[i4];
            #pragma unroll
            for (int ii = 0; ii < 4; ++ii) {
                const float hs_i = (ii == 0) ? hi.x : (ii == 1) ? hi.y : (ii == 2) ? hi.z : hi.w;
                const float* __restrict__ wr = wbase + (i4 * 4 + ii) * D;  // uniform -> s_load
                #pragma unroll
                for (int oo = 0; oo < 32; ++oo)
                    acc[oo] = fmaf(hs_i, wr[oo], acc[oo]);
            }
        }
    }

    // ---- pass 2: self = h[v] @ W_self  (all buckets) ----
    {
        const float4* __restrict__ hsrc = reinterpret_cast<const float4*>(h + (size_t)v * D);
        #pragma unroll
        for (int k = 0; k < 16; ++k) myrow4[k] = hsrc[k];

        const float* __restrict__ wbase = wself + obase;
        #pragma unroll 4
        for (int i4 = 0; i4 < 16; ++i4) {
            const float4 hi = myrow4[i4];
            #pragma unroll
            for (int ii = 0; ii < 4; ++ii) {
                const float hv_i = (ii == 0) ? hi.x : (ii == 1) ? hi.y : (ii == 2) ? hi.z : hi.w;
                const float* __restrict__ wr = wbase + (i4 * 4 + ii) * D;  // uniform -> s_load
                #pragma unroll
                for (int oo = 0; oo < 32; ++oo)
                    acc[oo] = fmaf(hv_i, wr[oo], acc[oo]);
            }
        }
    }

    // ---- store: 32 contiguous floats per lane (8x dwordx4) ----
    float4* __restrict__ orow = reinterpret_cast<float4*>(out + (size_t)v * D + obase);
    #pragma unroll
    for (int q = 0; q < 8; ++q)
        orow[q] = make_float4(acc[q * 4], acc[q * 4 + 1], acc[q * 4 + 2], acc[q * 4 + 3]);
}

extern "C" void kernel_launch(void* const* d_in, const int* in_sizes, int n_in,
                              void* d_out, int out_size, void* d_ws, size_t ws_size,
                              hipStream_t stream) {
    const float* h      = (const float*)d_in[0];
    const int*   edges  = (const int*)d_in[1];
    const float* weight = (const float*)d_in[2];
    const float* wself  = (const float*)d_in[3];
    float* out = (float*)d_out;

    char* ws = (char*)d_ws;
    u64*      packed  = (u64*)ws;
    int*      cursor  = (int*)(ws + WS_CURSOR);
    unsigned* rbucket = (unsigned*)(ws + WS_RBUCKET);
    unsigned* sbucket = (unsigned*)(ws + WS_SBUCKET);

    k_init<<<128, 256, 0, stream>>>(packed, cursor);
    k_scatter<<<(NE + 255) / 256, 256, 0, stream>>>(edges, packed);
    k_fill<<<FILL_BLOCKS, 256, 0, stream>>>(packed, cursor, rbucket, sbucket);
    k_compute<<<NREL * WPR + WPS, 64, 0, stream>>>(h, weight, wself, rbucket, sbucket, cursor, out);
}